// Round 1
// baseline (2687.402 us; speedup 1.0000x reference)
//
#include <hip/hip_runtime.h>
#include <math.h>

// Problem constants
#define NCASES   16
#define NPTS_BIG 65536
#define F1       512
#define OUT_B    4096

__device__ __forceinline__ float silu_f(float x) {
    return x / (1.0f + __expf(-x));
}

// Monotone float -> uint mapping (handles negatives) for atomicMax argmax.
__device__ __forceinline__ unsigned enc_f(float x) {
    unsigned u = __float_as_uint(x);
    return (u & 0x80000000u) ? ~u : (u | 0x80000000u);
}
__device__ __forceinline__ float dec_f(unsigned e) {
    unsigned u = (e & 0x80000000u) ? (e ^ 0x80000000u) : ~e;
    return __uint_as_float(u);
}

__global__ void k_init_u64(unsigned long long* a, int n) {
    int i = blockIdx.x * blockDim.x + threadIdx.x;
    if (i < n) a[i] = 0ull;
}

// Fused: per 64-point chunk compute mlp1 (3->64->128->512, SiLU each layer),
// then argmax over points per feature, combined globally via packed atomicMax.
// argOut[c*512+f] = (enc_f(maxval) << 32) | ~maxidx   (so bigger val wins;
// on equal val, smaller idx wins -> first-occurrence semantics).
__global__ __launch_bounds__(256, 2)
void k_mlp1_argmax(const float* __restrict__ pts, int nPts, int chunksPerBlock,
                   const float* __restrict__ W10, const float* __restrict__ b10,
                   const float* __restrict__ W11, const float* __restrict__ b11,
                   const float* __restrict__ W12, const float* __restrict__ b12,
                   unsigned long long* __restrict__ argOut)
{
    const int c   = blockIdx.y;
    const int tid = threadIdx.x;

    __shared__ float s_w10[3][64];       // 768 B
    __shared__ float s_b10[64];          // 256 B
    __shared__ float s_pts[64][3];       // 768 B
    __shared__ float s_h0[64][68];       // 17408 B (pad 68: +4 banks per row)
    __shared__ float s_h1[64][132];      // 33792 B (pad 132: +4 banks per row)
    __shared__ float s_redv[16][128];    // 8192 B
    __shared__ unsigned s_redi[16][128]; // 8192 B
    __shared__ float s_runv[512];        // 2048 B
    __shared__ unsigned s_runi[512];     // 2048 B
    // total ~72 KB -> 2 blocks/CU

    if (tid < 192) ((float*)s_w10)[tid] = W10[tid];
    if (tid < 64)  s_b10[tid] = b10[tid];
    s_runv[tid]       = -INFINITY;  s_runv[tid + 256] = -INFINITY;
    s_runi[tid]       = 0u;         s_runi[tid + 256] = 0u;

    const int tf = tid & 15;   // 16 feature-cols
    const int tp = tid >> 4;   // 16 point-rows
    const int j0 = tf * 8;     // 8 features per thread
    const int p0 = tp * 4;     // 4 points per thread

    const float* cpts = pts + (size_t)c * nPts * 3;

    #pragma unroll 1
    for (int ch = 0; ch < chunksPerBlock; ++ch) {
        const int pbase = (blockIdx.x * chunksPerBlock + ch) * 64;
        __syncthreads();   // previous iteration fully done with s_pts/s_h0/s_h1
        if (tid < 192) ((float*)s_pts)[tid] = cpts[(size_t)pbase * 3 + tid];
        __syncthreads();

        // ---- stage A: h0[64][64] = silu(pts @ W10 + b10) ----
        {
            const int j  = tid & 63;
            const int pb = tid >> 6;   // 0..3
            #pragma unroll
            for (int i = 0; i < 16; ++i) {
                const int p = i * 4 + pb;
                float v = s_pts[p][0] * s_w10[0][j]
                        + s_pts[p][1] * s_w10[1][j]
                        + s_pts[p][2] * s_w10[2][j] + s_b10[j];
                s_h0[p][j] = silu_f(v);
            }
        }
        __syncthreads();

        // ---- stage B: h1[64][128] = silu(h0 @ W11 + b11), K=64 ----
        {
            float acc[4][8];
            #pragma unroll
            for (int jj = 0; jj < 8; ++jj) {
                float bv = b11[j0 + jj];
                #pragma unroll
                for (int pp = 0; pp < 4; ++pp) acc[pp][jj] = bv;
            }
            #pragma unroll 2
            for (int kk = 0; kk < 64; kk += 4) {
                float4 a[4];
                #pragma unroll
                for (int pp = 0; pp < 4; ++pp)
                    a[pp] = *(const float4*)&s_h0[p0 + pp][kk];
                #pragma unroll
                for (int t = 0; t < 4; ++t) {
                    const float* wr = W11 + (size_t)(kk + t) * 128 + j0;
                    float4 w0 = *(const float4*)wr;
                    float4 w1 = *(const float4*)(wr + 4);
                    float wv[8] = {w0.x, w0.y, w0.z, w0.w, w1.x, w1.y, w1.z, w1.w};
                    #pragma unroll
                    for (int pp = 0; pp < 4; ++pp) {
                        float av = (t == 0) ? a[pp].x : (t == 1) ? a[pp].y
                                 : (t == 2) ? a[pp].z : a[pp].w;
                        #pragma unroll
                        for (int jj = 0; jj < 8; ++jj) acc[pp][jj] += av * wv[jj];
                    }
                }
            }
            #pragma unroll
            for (int pp = 0; pp < 4; ++pp) {
                float4 o0, o1;
                o0.x = silu_f(acc[pp][0]); o0.y = silu_f(acc[pp][1]);
                o0.z = silu_f(acc[pp][2]); o0.w = silu_f(acc[pp][3]);
                o1.x = silu_f(acc[pp][4]); o1.y = silu_f(acc[pp][5]);
                o1.z = silu_f(acc[pp][6]); o1.w = silu_f(acc[pp][7]);
                *(float4*)&s_h1[p0 + pp][j0]     = o0;
                *(float4*)&s_h1[p0 + pp][j0 + 4] = o1;
            }
        }
        __syncthreads();

        // ---- stage C: feats[64][512] = silu(h1 @ W12 + b12), K=128, 4 passes ----
        #pragma unroll 1
        for (int fg = 0; fg < 4; ++fg) {
            const int f0 = fg * 128;
            float acc[4][8];
            #pragma unroll
            for (int jj = 0; jj < 8; ++jj) {
                float bv = b12[f0 + j0 + jj];
                #pragma unroll
                for (int pp = 0; pp < 4; ++pp) acc[pp][jj] = bv;
            }
            #pragma unroll 2
            for (int kk = 0; kk < 128; kk += 4) {
                float4 a[4];
                #pragma unroll
                for (int pp = 0; pp < 4; ++pp)
                    a[pp] = *(const float4*)&s_h1[p0 + pp][kk];
                #pragma unroll
                for (int t = 0; t < 4; ++t) {
                    const float* wr = W12 + (size_t)(kk + t) * 512 + f0 + j0;
                    float4 w0 = *(const float4*)wr;
                    float4 w1 = *(const float4*)(wr + 4);
                    float wv[8] = {w0.x, w0.y, w0.z, w0.w, w1.x, w1.y, w1.z, w1.w};
                    #pragma unroll
                    for (int pp = 0; pp < 4; ++pp) {
                        float av = (t == 0) ? a[pp].x : (t == 1) ? a[pp].y
                                 : (t == 2) ? a[pp].z : a[pp].w;
                        #pragma unroll
                        for (int jj = 0; jj < 8; ++jj) acc[pp][jj] += av * wv[jj];
                    }
                }
            }
            // per-thread max over its 4 points (post-SiLU; SiLU is NOT monotone)
            #pragma unroll
            for (int jj = 0; jj < 8; ++jj) {
                float best = -INFINITY; unsigned bi = 0u;
                #pragma unroll
                for (int pp = 0; pp < 4; ++pp) {
                    float v = silu_f(acc[pp][jj]);
                    if (v > best) { best = v; bi = (unsigned)(pbase + p0 + pp); }
                }
                s_redv[tp][j0 + jj] = best;
                s_redi[tp][j0 + jj] = bi;
            }
            __syncthreads();
            if (tid < 128) {
                float best = s_redv[0][tid]; unsigned bi = s_redi[0][tid];
                #pragma unroll
                for (int r = 1; r < 16; ++r) {
                    float v = s_redv[r][tid]; unsigned i2 = s_redi[r][tid];
                    if (v > best || (v == best && i2 < bi)) { best = v; bi = i2; }
                }
                const int f = f0 + tid;
                if (best > s_runv[f] || (best == s_runv[f] && bi < s_runi[f])) {
                    s_runv[f] = best; s_runi[f] = bi;
                }
            }
            __syncthreads();
        }
    }

    // ---- flush per-block argmax to global (order-independent atomicMax) ----
    #pragma unroll
    for (int r = 0; r < 2; ++r) {
        const int f = tid + r * 256;
        unsigned long long key = ((unsigned long long)enc_f(s_runv[f]) << 32)
                               | (unsigned long long)(~s_runi[f]);
        atomicMax(&argOut[(size_t)c * 512 + f], key);
    }
}

// Gather critical points: fixed[c][f][:] = pts[c][idx[c][f]][:]
__global__ void k_gather(const float* __restrict__ pts,
                         const unsigned long long* __restrict__ argBuf,
                         float* __restrict__ fixedPts, int nPts)
{
    int id = blockIdx.x * blockDim.x + threadIdx.x;   // over 16*512
    if (id >= NCASES * F1) return;
    int c = id >> 9;
    unsigned idx = ~(unsigned)(argBuf[id] & 0xFFFFFFFFull);
    const float* src = pts + ((size_t)c * nPts + idx) * 3;
    float* dst = fixedPts + (size_t)id * 3;
    dst[0] = src[0]; dst[1] = src[1]; dst[2] = src[2];
}

// Head: latent0 -> silu(@W20+b20) -> @W21+b21. One block per case.
__global__ __launch_bounds__(256)
void k_head(const unsigned long long* __restrict__ argBuf2,
            const float* __restrict__ W20, const float* __restrict__ b20,
            const float* __restrict__ W21, const float* __restrict__ b21,
            float* __restrict__ latent)
{
    const int c = blockIdx.x, tid = threadIdx.x;
    __shared__ float l0[512];
    __shared__ float hh[256];
    l0[tid]       = dec_f((unsigned)(argBuf2[(size_t)c * 512 + tid] >> 32));
    l0[tid + 256] = dec_f((unsigned)(argBuf2[(size_t)c * 512 + tid + 256] >> 32));
    __syncthreads();
    float acc = b20[tid];
    for (int k = 0; k < 512; ++k) acc += l0[k] * W20[(size_t)k * 256 + tid];
    hh[tid] = silu_f(acc);
    __syncthreads();
    #pragma unroll
    for (int r = 0; r < 2; ++r) {
        int f = tid + r * 256;
        float a2 = b21[f];
        for (int k = 0; k < 256; ++k) a2 += hh[k] * W21[(size_t)k * 512 + f];
        latent[(size_t)c * 512 + f] = a2;
    }
}

// out[b][:] = latent[x[b]][:]
__global__ void k_scatter(const int* __restrict__ x,
                          const float* __restrict__ latent,
                          float* __restrict__ out)
{
    const int b = blockIdx.x, t = threadIdx.x;   // 128 threads, float4 each
    int cid = x[b];
    const float4* src = (const float4*)(latent + (size_t)cid * 512);
    float4* dst = (float4*)(out + (size_t)b * 512);
    dst[t] = src[t];
}

extern "C" void kernel_launch(void* const* d_in, const int* in_sizes, int n_in,
                              void* d_out, int out_size, void* d_ws, size_t ws_size,
                              hipStream_t stream)
{
    const float* pts = (const float*)d_in[0];
    const float* W10 = (const float*)d_in[1];
    const float* b10 = (const float*)d_in[2];
    const float* W11 = (const float*)d_in[3];
    const float* b11 = (const float*)d_in[4];
    const float* W12 = (const float*)d_in[5];
    const float* b12 = (const float*)d_in[6];
    const float* W20 = (const float*)d_in[7];
    const float* b20 = (const float*)d_in[8];
    const float* W21 = (const float*)d_in[9];
    const float* b21 = (const float*)d_in[10];
    const int*   x   = (const int*)d_in[11];
    float* out = (float*)d_out;

    // Workspace layout (re-poisoned every call -> re-init every call):
    char* ws = (char*)d_ws;
    unsigned long long* argBuf  = (unsigned long long*)ws;             // 16*512 u64 = 64 KB
    unsigned long long* argBuf2 = (unsigned long long*)(ws + 65536);   // 64 KB
    float* fixedPts             = (float*)(ws + 131072);               // 16*512*3 f32 = 96 KB
    float* latent               = (float*)(ws + 131072 + 98304);      // 16*512 f32 = 32 KB

    // zero both argmax buffers (contiguous)
    k_init_u64<<<dim3(64), dim3(256), 0, stream>>>(argBuf, NCASES * F1 * 2);

    // Phase 1: big MLP + argmax over 65536 points/case
    k_mlp1_argmax<<<dim3(128, NCASES), dim3(256), 0, stream>>>(
        pts, NPTS_BIG, 8, W10, b10, W11, b11, W12, b12, argBuf);

    // Phase 2: gather critical points
    k_gather<<<dim3(32), dim3(256), 0, stream>>>(pts, argBuf, fixedPts, NPTS_BIG);

    // Phase 3: MLP over 512 critical points/case + max (idx unused)
    k_mlp1_argmax<<<dim3(8, NCASES), dim3(256), 0, stream>>>(
        fixedPts, F1, 1, W10, b10, W11, b11, W12, b12, argBuf2);

    // Phase 4: head MLP per case
    k_head<<<dim3(NCASES), dim3(256), 0, stream>>>(argBuf2, W20, b20, W21, b21, latent);

    // Phase 5: scatter latent rows to output by case id
    k_scatter<<<dim3(OUT_B), dim3(128), 0, stream>>>(x, latent, out);
}

// Round 2
// 285.130 us; speedup vs baseline: 9.4252x; 9.4252x over previous
//
#include <hip/hip_runtime.h>
#include <math.h>

// Problem constants
#define NCASES   16
#define NPTS_BIG 65536
#define F1       512
#define OUT_B    4096

typedef __attribute__((ext_vector_type(8))) short  short8;   // 8 bf16 = 4 VGPR (MFMA A/B frag)
typedef __attribute__((ext_vector_type(4))) float  floatx4;  // MFMA C/D frag

__device__ __forceinline__ float silu_f(float x) {
    return x * __builtin_amdgcn_rcpf(1.0f + __expf(-x));
}

// round-to-nearest-even fp32 -> bf16 (as raw u16)
__device__ __forceinline__ unsigned short f2bf(float x) {
    unsigned u = __float_as_uint(x);
    u += 0x7FFFu + ((u >> 16) & 1u);
    return (unsigned short)(u >> 16);
}

// Monotone float -> uint mapping (handles negatives) for atomicMax argmax.
__device__ __forceinline__ unsigned enc_f(float x) {
    unsigned u = __float_as_uint(x);
    return (u & 0x80000000u) ? ~u : (u | 0x80000000u);
}
__device__ __forceinline__ float dec_f(unsigned e) {
    unsigned u = (e & 0x80000000u) ? (e ^ 0x80000000u) : ~e;
    return __uint_as_float(u);
}

__global__ void k_init_u64(unsigned long long* a, int n) {
    int i = blockIdx.x * blockDim.x + threadIdx.x;
    if (i < n) a[i] = 0ull;
}

// Pre-swizzle W11/W12 into MFMA B-fragment order (bf16), so each lane's frag is a
// single contiguous 16B load.  B-layout for 16x16x32: B[k = KT*32 + (lane>>4)*8 + j][n].
// BcWs: [w(8)][NT(4)][KT(4)][lane(64)][j(8)]  (W12, 128 KB)
// BbWs: [w(8)][KT(2)][lane(64)][j(8)]        (W11, 16 KB)
__global__ void k_prep(const float* __restrict__ W11, const float* __restrict__ W12,
                       unsigned short* __restrict__ BbWs, unsigned short* __restrict__ BcWs)
{
    int i = blockIdx.x * 256 + threadIdx.x;
    if (i < 65536) {
        int j = i & 7, l = (i >> 3) & 63, t = i >> 9;     // t = w*16 + NT*4 + KT
        int KT = t & 3, NT = (t >> 2) & 3, w = t >> 4;
        int k = KT * 32 + (l >> 4) * 8 + j;
        int f = w * 64 + NT * 16 + (l & 15);
        BcWs[i] = f2bf(W12[(size_t)k * 512 + f]);
    }
    if (i < 8192) {
        int j = i & 7, l = (i >> 3) & 63, t = i >> 9;     // t = w*2 + KT
        int KT = t & 1, w = t >> 1;
        int k = KT * 32 + (l >> 4) * 8 + j;
        int f = w * 16 + (l & 15);
        BbWs[i] = f2bf(W11[(size_t)k * 128 + f]);
    }
}

// Fused mlp1 + per-feature argmax of PRE-ACTIVATION (valid: silu monotone for x>=-1.278
// and silu(x)<0 for x<0; per-feature max pre-act > 0 w.o.p. since biases are zero).
// Bias b12 added after the max (constant per feature), silu applied downstream (k_head).
// argOut[c*512+f] = (enc_f(maxPre + b12) << 32) | ~maxidx  -> bigger val wins, then lower idx.
// 512 threads = 8 waves; wave w owns feature slice [w*64, w*64+64).  W12/W11 B-frags
// persistent in registers (64+8 VGPR/lane); h0/h1 round-trip through LDS as bf16.
__global__ __launch_bounds__(512, 2)
void k_mlp1_argmax(const float* __restrict__ pts, int nPts, int chunksPerBlock,
                   const float* __restrict__ W10, const float* __restrict__ b10,
                   const float* __restrict__ b11, const float* __restrict__ b12,
                   const unsigned short* __restrict__ BbWs,
                   const unsigned short* __restrict__ BcWs,
                   unsigned long long* __restrict__ argOut)
{
    const int c   = blockIdx.y;
    const int tid = threadIdx.x;
    const int w   = tid >> 6;   // wave 0..7
    const int l   = tid & 63;   // lane
    const int lm  = l & 15;     // m/n within 16x16 tile
    const int q   = l >> 4;     // quad

    __shared__ float s_w10[3][64];
    __shared__ float s_b10v[64];
    __shared__ __align__(16) unsigned short s_h0[64][72];   // bf16, stride 144B (16B-mult, bank-safe)
    __shared__ __align__(16) unsigned short s_h1[64][136];  // bf16, stride 272B (16B-mult, bank-safe)

    if (tid < 192) ((float*)s_w10)[tid] = W10[tid];
    if (tid < 64)  s_b10v[tid] = b10[tid];

    // persistent B fragments (registers)
    short8 Bc[16];   // [NT*4+KT] for W12 slice
    #pragma unroll
    for (int t = 0; t < 16; ++t)
        Bc[t] = *(const short8*)(BcWs + (size_t)((w * 16 + t) * 64 + l) * 8);
    short8 Bb[2];    // [KT] for W11 slice
    #pragma unroll
    for (int t = 0; t < 2; ++t)
        Bb[t] = *(const short8*)(BbWs + (size_t)((w * 2 + t) * 64 + l) * 8);

    const float bias11 = b11[w * 16 + lm];
    float bias12[4];
    #pragma unroll
    for (int NT = 0; NT < 4; ++NT) bias12[NT] = b12[w * 64 + NT * 16 + lm];

    float    bestv[4];
    unsigned besti[4];
    #pragma unroll
    for (int NT = 0; NT < 4; ++NT) { bestv[NT] = -INFINITY; besti[NT] = 0u; }

    const float* cpts = pts + (size_t)c * nPts * 3;

    for (int ch = 0; ch < chunksPerBlock; ++ch) {
        const int pbase = (blockIdx.x * chunksPerBlock + ch) * 64;
        __syncthreads();   // prev chunk's stage-C reads of s_h1 / stage-B reads of s_h0 done

        // ---- stage A: h0[64][64] = silu(pts @ W10 + b10), one thread = 1 point x 8 feats ----
        {
            const int p = tid >> 3, f0 = (tid & 7) * 8;
            const float x = cpts[(size_t)(pbase + p) * 3 + 0];
            const float y = cpts[(size_t)(pbase + p) * 3 + 1];
            const float z = cpts[(size_t)(pbase + p) * 3 + 2];
            short8 hv;
            #pragma unroll
            for (int jj = 0; jj < 8; ++jj) {
                const int f = f0 + jj;
                float v = x * s_w10[0][f] + y * s_w10[1][f] + z * s_w10[2][f] + s_b10v[f];
                hv[jj] = (short)f2bf(silu_f(v));
            }
            *(short8*)&s_h0[p][f0] = hv;   // 16B aligned (144*p + 2*f0)
        }
        __syncthreads();

        // ---- stage B: h1[64][128] = silu(h0 @ W11 + b11); wave w -> feature tile w ----
        #pragma unroll
        for (int MT = 0; MT < 4; ++MT) {
            short8 a0 = *(const short8*)&s_h0[MT * 16 + lm][q * 8];        // A[m=lm][k=q*8+j], KT=0
            short8 a1 = *(const short8*)&s_h0[MT * 16 + lm][32 + q * 8];   // KT=1
            floatx4 acc = {0.f, 0.f, 0.f, 0.f};
            acc = __builtin_amdgcn_mfma_f32_16x16x32_bf16(a0, Bb[0], acc, 0, 0, 0);
            acc = __builtin_amdgcn_mfma_f32_16x16x32_bf16(a1, Bb[1], acc, 0, 0, 0);
            #pragma unroll
            for (int r = 0; r < 4; ++r)   // C/D: row = q*4+r (point), col = lm (feature)
                s_h1[MT * 16 + q * 4 + r][w * 16 + lm] = f2bf(silu_f(acc[r] + bias11));
        }
        __syncthreads();

        // ---- stage C: pre-act feats = h1 @ W12; track per-feature argmax in registers ----
        #pragma unroll
        for (int MT = 0; MT < 4; ++MT) {
            short8 a[4];
            #pragma unroll
            for (int KT = 0; KT < 4; ++KT)
                a[KT] = *(const short8*)&s_h1[MT * 16 + lm][KT * 32 + q * 8];
            #pragma unroll
            for (int NT = 0; NT < 4; ++NT) {
                floatx4 acc = {0.f, 0.f, 0.f, 0.f};
                #pragma unroll
                for (int KT = 0; KT < 4; ++KT)
                    acc = __builtin_amdgcn_mfma_f32_16x16x32_bf16(a[KT], Bc[NT * 4 + KT], acc, 0, 0, 0);
                #pragma unroll
                for (int r = 0; r < 4; ++r) {   // ascending point order -> strict > keeps first occurrence
                    float v = acc[r];
                    if (v > bestv[NT]) {
                        bestv[NT] = v;
                        besti[NT] = (unsigned)(pbase + MT * 16 + q * 4 + r);
                    }
                }
            }
        }
    }

    // ---- flush: combine quads via shfl, add bias, one atomicMax per (feature) ----
    #pragma unroll
    for (int NT = 0; NT < 4; ++NT) {
        float v = bestv[NT]; unsigned i = besti[NT];
        #pragma unroll
        for (int m = 16; m <= 32; m <<= 1) {
            float    vo = __shfl_xor(v, m, 64);
            unsigned io = __shfl_xor(i, m, 64);
            if (vo > v || (vo == v && io < i)) { v = vo; i = io; }
        }
        if (q == 0) {
            v += bias12[NT];
            unsigned long long key = ((unsigned long long)enc_f(v) << 32)
                                   | (unsigned long long)(~i);
            atomicMax(&argOut[(size_t)c * 512 + w * 64 + NT * 16 + lm], key);
        }
    }
}

// Gather critical points: fixed[c][f][:] = pts[c][idx[c][f]][:]
__global__ void k_gather(const float* __restrict__ pts,
                         const unsigned long long* __restrict__ argBuf,
                         float* __restrict__ fixedPts, int nPts)
{
    int id = blockIdx.x * blockDim.x + threadIdx.x;   // over 16*512
    if (id >= NCASES * F1) return;
    int c = id >> 9;
    unsigned idx = ~(unsigned)(argBuf[id] & 0xFFFFFFFFull);
    const float* src = pts + ((size_t)c * nPts + idx) * 3;
    float* dst = fixedPts + (size_t)id * 3;
    dst[0] = src[0]; dst[1] = src[1]; dst[2] = src[2];
}

// Head: latent0 = silu(decoded max pre-act) -> silu(@W20+b20) -> @W21+b21. One block/case.
__global__ __launch_bounds__(256)
void k_head(const unsigned long long* __restrict__ argBuf2,
            const float* __restrict__ W20, const float* __restrict__ b20,
            const float* __restrict__ W21, const float* __restrict__ b21,
            float* __restrict__ latent)
{
    const int c = blockIdx.x, tid = threadIdx.x;
    __shared__ float l0[512];
    __shared__ float hh[256];
    l0[tid]       = silu_f(dec_f((unsigned)(argBuf2[(size_t)c * 512 + tid] >> 32)));
    l0[tid + 256] = silu_f(dec_f((unsigned)(argBuf2[(size_t)c * 512 + tid + 256] >> 32)));
    __syncthreads();
    float acc = b20[tid];
    for (int k = 0; k < 512; ++k) acc += l0[k] * W20[(size_t)k * 256 + tid];
    hh[tid] = silu_f(acc);
    __syncthreads();
    #pragma unroll
    for (int r = 0; r < 2; ++r) {
        int f = tid + r * 256;
        float a2 = b21[f];
        for (int k = 0; k < 256; ++k) a2 += hh[k] * W21[(size_t)k * 512 + f];
        latent[(size_t)c * 512 + f] = a2;
    }
}

// out[b][:] = latent[x[b]][:]
__global__ void k_scatter(const int* __restrict__ x,
                          const float* __restrict__ latent,
                          float* __restrict__ out)
{
    const int b = blockIdx.x, t = threadIdx.x;   // 128 threads, float4 each
    int cid = x[b];
    const float4* src = (const float4*)(latent + (size_t)cid * 512);
    float4* dst = (float4*)(out + (size_t)b * 512);
    dst[t] = src[t];
}

extern "C" void kernel_launch(void* const* d_in, const int* in_sizes, int n_in,
                              void* d_out, int out_size, void* d_ws, size_t ws_size,
                              hipStream_t stream)
{
    const float* pts = (const float*)d_in[0];
    const float* W10 = (const float*)d_in[1];
    const float* b10 = (const float*)d_in[2];
    const float* W11 = (const float*)d_in[3];
    const float* b11 = (const float*)d_in[4];
    const float* W12 = (const float*)d_in[5];
    const float* b12 = (const float*)d_in[6];
    const float* W20 = (const float*)d_in[7];
    const float* b20 = (const float*)d_in[8];
    const float* W21 = (const float*)d_in[9];
    const float* b21 = (const float*)d_in[10];
    const int*   x   = (const int*)d_in[11];
    float* out = (float*)d_out;

    // Workspace layout (re-poisoned every call -> rebuild every call):
    char* ws = (char*)d_ws;
    unsigned long long* argBuf  = (unsigned long long*)ws;              //  64 KB
    unsigned long long* argBuf2 = (unsigned long long*)(ws + 65536);    //  64 KB
    float* fixedPts             = (float*)(ws + 131072);                //  96 KB
    float* latent               = (float*)(ws + 229376);                //  32 KB
    unsigned short* BbWs        = (unsigned short*)(ws + 262144);       //  16 KB
    unsigned short* BcWs        = (unsigned short*)(ws + 278528);       // 128 KB  (total 400 KB)

    // zero both argmax buffers (contiguous)
    k_init_u64<<<dim3(64), dim3(256), 0, stream>>>(argBuf, NCASES * F1 * 2);

    // pre-swizzle weights into MFMA B-frag order (bf16)
    k_prep<<<dim3(256), dim3(256), 0, stream>>>(W11, W12, BbWs, BcWs);

    // Phase 1: big MLP + argmax over 65536 points/case
    k_mlp1_argmax<<<dim3(128, NCASES), dim3(512), 0, stream>>>(
        pts, NPTS_BIG, 8, W10, b10, b11, b12, BbWs, BcWs, argBuf);

    // Phase 2: gather critical points
    k_gather<<<dim3(32), dim3(256), 0, stream>>>(pts, argBuf, fixedPts, NPTS_BIG);

    // Phase 3: MLP over 512 critical points/case + max (idx unused)
    k_mlp1_argmax<<<dim3(8, NCASES), dim3(512), 0, stream>>>(
        fixedPts, F1, 1, W10, b10, b11, b12, BbWs, BcWs, argBuf2);

    // Phase 4: head MLP per case (applies silu to decoded max)
    k_head<<<dim3(NCASES), dim3(256), 0, stream>>>(argBuf2, W20, b20, W21, b21, latent);

    // Phase 5: scatter latent rows to output by case id
    k_scatter<<<dim3(OUT_B), dim3(128), 0, stream>>>(x, latent, out);
}